// Round 1
// baseline (139.653 us; speedup 1.0000x reference)
//
#include <hip/hip_runtime.h>

#define B_ 2048
#define V_ 2048
#define C_ 512
#define M_ 8
#define H_ 16
#define NB 8          // rows per block (weight-reuse factor)
#define CHUNK 256     // columns per block == blockDim.x

__device__ __forceinline__ float fast_exp2(float x) { return __builtin_amdgcn_exp2f(x); }
__device__ __forceinline__ float fast_rcp(float x)  { return __builtin_amdgcn_rcpf(x); }
// tanh(x) = 1 - 2/(exp2(2*log2e*x) + 1); saturates correctly for |x| large.
__device__ __forceinline__ float fast_tanh(float x) {
    float t = fast_exp2(x * 2.88539008177793f);
    return 1.0f - 2.0f * fast_rcp(t + 1.0f);
}

__global__ __launch_bounds__(256) void grad_attn_kernel(
    const float* __restrict__ preds,
    const int*   __restrict__ mask_ids,
    const float* __restrict__ W1,
    const float* __restrict__ b1,
    const float* __restrict__ W2,
    float*       __restrict__ out)
{
    const int tid    = threadIdx.x;
    const int chunk  = blockIdx.x;   // 0..V_/CHUNK-1
    const int rowgrp = blockIdx.y;   // 0..B_/NB-1
    const int b0 = rowgrp * NB;
    const int c0 = chunk * CHUNK;

    if (c0 >= C_) {
        // Pure copy region: cols [c0, c0+CHUNK) of rows b0..b0+NB-1.
        #pragma unroll
        for (int i = tid; i < NB * (CHUNK / 4); i += 256) {
            int r = i / (CHUNK / 4);
            int j = i % (CHUNK / 4);
            const float4* src = reinterpret_cast<const float4*>(preds + (size_t)(b0 + r) * V_ + c0);
            float4*       dst = reinterpret_cast<float4*>(out + (size_t)(b0 + r) * V_ + c0);
            dst[j] = src[j];
        }
        return;
    }

    const int c = c0 + tid;   // each thread owns one column c for NB rows

    // ---- load this column's weights into registers (b2 cancels in softmax) ----
    float w1a[H_], w1b[H_], bb[H_], w2[H_];
    {
        const float4* W1v = reinterpret_cast<const float4*>(W1 + (size_t)c * 2 * H_);
        const float4* b1v = reinterpret_cast<const float4*>(b1 + (size_t)c * H_);
        const float4* W2v = reinterpret_cast<const float4*>(W2 + (size_t)c * H_);
        #pragma unroll
        for (int i = 0; i < H_ / 4; ++i) {
            *reinterpret_cast<float4*>(&w1a[4 * i]) = W1v[i];
            *reinterpret_cast<float4*>(&w1b[4 * i]) = W1v[H_ / 4 + i];
            *reinterpret_cast<float4*>(&bb[4 * i])  = b1v[i];
            *reinterpret_cast<float4*>(&w2[4 * i])  = W2v[i];
        }
    }

    // ---- gather indices for this column ----
    int midx[M_];
    {
        const int4* mi = reinterpret_cast<const int4*>(mask_ids + (size_t)c * M_);
        int4 a = mi[0], b = mi[1];
        midx[0] = a.x; midx[1] = a.y; midx[2] = a.z; midx[3] = a.w;
        midx[4] = b.x; midx[5] = b.y; midx[6] = b.z; midx[7] = b.w;
    }

    for (int r = 0; r < NB; ++r) {
        const float* row = preds + (size_t)(b0 + r) * V_;
        float ha = row[c];
        float hm[M_];
        #pragma unroll
        for (int m = 0; m < M_; ++m) hm[m] = row[midx[m]];

        float score[M_];
        #pragma unroll
        for (int m = 0; m < M_; ++m) score[m] = 0.0f;

        #pragma unroll
        for (int h = 0; h < H_; ++h) {
            float pa  = fmaf(ha, w1a[h], bb[h]);
            float wb  = w1b[h];
            float w2h = w2[h];
            #pragma unroll
            for (int m = 0; m < M_; ++m) {
                float t = fast_tanh(fmaf(hm[m], wb, pa));
                score[m] = fmaf(t, w2h, score[m]);
            }
        }

        // softmax over M_ + weighted sum (all in registers)
        float mx = score[0];
        #pragma unroll
        for (int m = 1; m < M_; ++m) mx = fmaxf(mx, score[m]);
        float sum = 0.0f, ws = 0.0f;
        #pragma unroll
        for (int m = 0; m < M_; ++m) {
            float e = fast_exp2((score[m] - mx) * 1.4426950408889634f);
            sum += e;
            ws = fmaf(e, hm[m], ws);
        }
        float corrected = fmaxf(ha, fmaf(ws, fast_rcp(sum), 1e-6f));
        out[(size_t)(b0 + r) * V_ + c] = corrected;
    }
}

extern "C" void kernel_launch(void* const* d_in, const int* in_sizes, int n_in,
                              void* d_out, int out_size, void* d_ws, size_t ws_size,
                              hipStream_t stream) {
    const float* preds    = (const float*)d_in[0];
    // d_in[1] = ground_truth (unused by reference)
    const int*   mask_ids = (const int*)d_in[2];
    const float* W1       = (const float*)d_in[3];
    const float* b1       = (const float*)d_in[4];
    const float* W2       = (const float*)d_in[5];
    // d_in[6] = b2 — uniform shift along softmax axis, cancels; not needed.
    float* out = (float*)d_out;

    dim3 grid(V_ / CHUNK, B_ / NB);
    dim3 block(256);
    grad_attn_kernel<<<grid, block, 0, stream>>>(preds, mask_ids, W1, b1, W2, out);
}

// Round 2
// 43.826 us; speedup vs baseline: 3.1865x; 3.1865x over previous
//
#include <hip/hip_runtime.h>

#define B_ 2048
#define V_ 2048
#define C_ 512
#define M_ 8
#define H_ 16
#define NB 2            // rows per compute block (parallelism > weight reuse)
#define CHUNK 256       // columns per compute block == blockDim.x
#define NCOMPUTE ((C_ / CHUNK) * (B_ / NB))   // 2 * 1024 = 2048 compute blocks
#define NCOPY (B_ / 2)                        // 1024 copy blocks, 2 rows each

__device__ __forceinline__ float fast_exp2(float x) { return __builtin_amdgcn_exp2f(x); }
__device__ __forceinline__ float fast_rcp(float x)  { return __builtin_amdgcn_rcpf(x); }
// tanh(x) = 1 - 2/(exp2(2*log2e*x) + 1); saturates correctly for |x| large.
__device__ __forceinline__ float fast_tanh(float x) {
    float t = fast_exp2(x * 2.88539008177793f);
    return 1.0f - 2.0f * fast_rcp(t + 1.0f);
}

__global__ __launch_bounds__(256) void grad_attn_kernel(
    const float* __restrict__ preds,
    const int*   __restrict__ mask_ids,
    const float* __restrict__ W1,
    const float* __restrict__ b1,
    const float* __restrict__ W2,
    float*       __restrict__ out)
{
    const int tid = threadIdx.x;
    const int bi  = blockIdx.x;

    if (bi >= NCOMPUTE) {
        // ---- pure copy region: cols [C_, V_) of 2 rows ----
        const int r0 = (bi - NCOMPUTE) * 2;
        #pragma unroll
        for (int r = 0; r < 2; ++r) {
            const float4* src = reinterpret_cast<const float4*>(preds + (size_t)(r0 + r) * V_ + C_);
            float4*       dst = reinterpret_cast<float4*>(out + (size_t)(r0 + r) * V_ + C_);
            // (V_-C_)/4 = 384 float4 per row
            #pragma unroll
            for (int j = tid; j < (V_ - C_) / 4; j += 256) dst[j] = src[j];
        }
        return;
    }

    const int chunk  = bi & 1;        // 0..C_/CHUNK-1
    const int rowgrp = bi >> 1;       // 0..B_/NB-1
    const int b0 = rowgrp * NB;
    const int c  = chunk * CHUNK + tid;   // each thread owns one column c

    // ---- load this column's weights into registers (b2 cancels in softmax) ----
    float w1a[H_], w1b[H_], bb[H_], w2[H_];
    {
        const float4* W1v = reinterpret_cast<const float4*>(W1 + (size_t)c * 2 * H_);
        const float4* b1v = reinterpret_cast<const float4*>(b1 + (size_t)c * H_);
        const float4* W2v = reinterpret_cast<const float4*>(W2 + (size_t)c * H_);
        #pragma unroll
        for (int i = 0; i < H_ / 4; ++i) {
            *reinterpret_cast<float4*>(&w1a[4 * i]) = W1v[i];
            *reinterpret_cast<float4*>(&w1b[4 * i]) = W1v[H_ / 4 + i];
            *reinterpret_cast<float4*>(&bb[4 * i])  = b1v[i];
            *reinterpret_cast<float4*>(&w2[4 * i])  = W2v[i];
        }
    }

    // ---- gather indices for this column ----
    int midx[M_];
    {
        const int4* mi = reinterpret_cast<const int4*>(mask_ids + (size_t)c * M_);
        int4 a = mi[0], b = mi[1];
        midx[0] = a.x; midx[1] = a.y; midx[2] = a.z; midx[3] = a.w;
        midx[4] = b.x; midx[5] = b.y; midx[6] = b.z; midx[7] = b.w;
    }

    #pragma unroll
    for (int r = 0; r < NB; ++r) {
        const float* row = preds + (size_t)(b0 + r) * V_;
        float ha = row[c];
        float hm[M_];
        #pragma unroll
        for (int m = 0; m < M_; ++m) hm[m] = row[midx[m]];

        float score[M_];
        #pragma unroll
        for (int m = 0; m < M_; ++m) score[m] = 0.0f;

        #pragma unroll
        for (int h = 0; h < H_; ++h) {
            float pa  = fmaf(ha, w1a[h], bb[h]);
            float wb  = w1b[h];
            float w2h = w2[h];
            #pragma unroll
            for (int m = 0; m < M_; ++m) {
                float t = fast_tanh(fmaf(hm[m], wb, pa));
                score[m] = fmaf(t, w2h, score[m]);
            }
        }

        // softmax over M_ + weighted sum (all in registers)
        float mx = score[0];
        #pragma unroll
        for (int m = 1; m < M_; ++m) mx = fmaxf(mx, score[m]);
        float sum = 0.0f, ws = 0.0f;
        #pragma unroll
        for (int m = 0; m < M_; ++m) {
            float e = fast_exp2((score[m] - mx) * 1.4426950408889634f);
            sum += e;
            ws = fmaf(e, hm[m], ws);
        }
        float corrected = fmaxf(ha, fmaf(ws, fast_rcp(sum), 1e-6f));
        out[(size_t)(b0 + r) * V_ + c] = corrected;
    }
}

extern "C" void kernel_launch(void* const* d_in, const int* in_sizes, int n_in,
                              void* d_out, int out_size, void* d_ws, size_t ws_size,
                              hipStream_t stream) {
    const float* preds    = (const float*)d_in[0];
    // d_in[1] = ground_truth (unused by reference)
    const int*   mask_ids = (const int*)d_in[2];
    const float* W1       = (const float*)d_in[3];
    const float* b1       = (const float*)d_in[4];
    const float* W2       = (const float*)d_in[5];
    // d_in[6] = b2 — uniform shift along softmax axis, cancels; not needed.
    float* out = (float*)d_out;

    dim3 grid(NCOMPUTE + NCOPY);
    dim3 block(256);
    grad_attn_kernel<<<grid, block, 0, stream>>>(preds, mask_ids, W1, b1, W2, out);
}

// Round 3
// 34.973 us; speedup vs baseline: 3.9932x; 1.2531x over previous
//
#include <hip/hip_runtime.h>

#define B_ 2048
#define V_ 2048
#define C_ 512
#define M_ 8
#define H_ 16
#define NB 2            // rows per compute block
#define CHUNK 256       // columns per compute block == blockDim.x
#define NCOMPUTE ((C_ / CHUNK) * (B_ / NB))   // 2048 compute blocks (= 8/CU, exact fill)
#define NCOPY (B_ / 2)                        // 1024 copy blocks, 2 rows each

typedef float f32x2 __attribute__((ext_vector_type(2)));

__device__ __forceinline__ float fast_exp2(float x) { return __builtin_amdgcn_exp2f(x); }
__device__ __forceinline__ float fast_rcp(float x)  { return __builtin_amdgcn_rcpf(x); }

#define K_SCALE 2.885390081777927f      // 2*log2(e): tanh(x) = 1 - 2/(exp2(K*x)+1)
#define LOG2E   1.4426950408889634f

__global__ __launch_bounds__(256) void grad_attn_kernel(
    const float* __restrict__ preds,
    const int*   __restrict__ mask_ids,
    const float* __restrict__ W1,
    const float* __restrict__ b1,
    const float* __restrict__ W2,
    float*       __restrict__ out)
{
    const int tid = threadIdx.x;
    const int bi  = blockIdx.x;

    if (bi >= NCOMPUTE) {
        // ---- pure copy region: cols [C_, V_) of 2 rows ----
        const int r0 = (bi - NCOMPUTE) * 2;
        #pragma unroll
        for (int r = 0; r < 2; ++r) {
            const float4* src = reinterpret_cast<const float4*>(preds + (size_t)(r0 + r) * V_ + C_);
            float4*       dst = reinterpret_cast<float4*>(out + (size_t)(r0 + r) * V_ + C_);
            #pragma unroll
            for (int j = tid; j < (V_ - C_) / 4; j += 256) dst[j] = src[j];
        }
        return;
    }

    const int chunk  = bi & 1;
    const int rowgrp = bi >> 1;
    const int b0 = rowgrp * NB;
    const int c  = chunk * CHUNK + tid;

    // ---- weights in registers, pre-scaled.  b2 cancels in softmax. ----
    float w1a[H_], w1b[H_], bb[H_], w2n[H_];
    float base = 0.0f;
    {
        const float4* W1v = reinterpret_cast<const float4*>(W1 + (size_t)c * 2 * H_);
        const float4* b1v = reinterpret_cast<const float4*>(b1 + (size_t)c * H_);
        const float4* W2v = reinterpret_cast<const float4*>(W2 + (size_t)c * H_);
        #pragma unroll
        for (int i = 0; i < H_ / 4; ++i) {
            float4 a = W1v[i], bvk = W1v[H_ / 4 + i], bv = b1v[i], wv = W2v[i];
            w1a[4*i+0] = a.x * K_SCALE;  w1a[4*i+1] = a.y * K_SCALE;
            w1a[4*i+2] = a.z * K_SCALE;  w1a[4*i+3] = a.w * K_SCALE;
            w1b[4*i+0] = bvk.x * K_SCALE; w1b[4*i+1] = bvk.y * K_SCALE;
            w1b[4*i+2] = bvk.z * K_SCALE; w1b[4*i+3] = bvk.w * K_SCALE;
            bb[4*i+0] = bv.x * K_SCALE;  bb[4*i+1] = bv.y * K_SCALE;
            bb[4*i+2] = bv.z * K_SCALE;  bb[4*i+3] = bv.w * K_SCALE;
            w2n[4*i+0] = -2.0f * wv.x;   w2n[4*i+1] = -2.0f * wv.y;
            w2n[4*i+2] = -2.0f * wv.z;   w2n[4*i+3] = -2.0f * wv.w;
            base += wv.x + wv.y + wv.z + wv.w;
        }
    }

    int midx[M_];
    {
        const int4* mi = reinterpret_cast<const int4*>(mask_ids + (size_t)c * M_);
        int4 a = mi[0], b = mi[1];
        midx[0] = a.x; midx[1] = a.y; midx[2] = a.z; midx[3] = a.w;
        midx[4] = b.x; midx[5] = b.y; midx[6] = b.z; midx[7] = b.w;
    }

    #pragma unroll
    for (int r = 0; r < NB; ++r) {
        const float* row = preds + (size_t)(b0 + r) * V_;
        float ha = row[c];
        f32x2 hm2[M_ / 2];
        #pragma unroll
        for (int p = 0; p < M_ / 2; ++p) {
            hm2[p].x = row[midx[2 * p]];
            hm2[p].y = row[midx[2 * p + 1]];
        }

        // sc accumulates  -2 * sum_h w2[h] * rcp(exp2(K*arg)+1)
        f32x2 sc[M_ / 2];
        #pragma unroll
        for (int p = 0; p < M_ / 2; ++p) sc[p] = (f32x2){0.0f, 0.0f};

        #pragma unroll
        for (int h = 0; h < H_; ++h) {
            float pa = fmaf(ha, w1a[h], bb[h]);
            f32x2 pav = {pa, pa};
            f32x2 wbv = {w1b[h], w1b[h]};
            f32x2 w2v = {w2n[h], w2n[h]};
            #pragma unroll
            for (int p = 0; p < M_ / 2; ++p) {
                f32x2 arg = __builtin_elementwise_fma(hm2[p], wbv, pav);   // v_pk_fma_f32
                f32x2 e;
                e.x = fast_exp2(arg.x);
                e.y = fast_exp2(arg.y);
                e = e + (f32x2){1.0f, 1.0f};                               // v_pk_add_f32
                f32x2 rc;
                rc.x = fast_rcp(e.x);
                rc.y = fast_rcp(e.y);
                sc[p] = __builtin_elementwise_fma(rc, w2v, sc[p]);         // v_pk_fma_f32
            }
        }

        // softmax over M (no max-subtract: |score| <= sum|w2| ~ 6, exp2 safe)
        const float basel = base * LOG2E;
        f32x2 baselv = {basel, basel};
        f32x2 l2ev   = {LOG2E, LOG2E};
        f32x2 ex[M_ / 2];
        #pragma unroll
        for (int p = 0; p < M_ / 2; ++p) {
            f32x2 sl = __builtin_elementwise_fma(sc[p], l2ev, baselv);     // score*log2e
            ex[p].x = fast_exp2(sl.x);
            ex[p].y = fast_exp2(sl.y);
        }
        f32x2 s2 = (ex[0] + ex[1]) + (ex[2] + ex[3]);
        f32x2 w2s = __builtin_elementwise_fma(ex[0], hm2[0],
                    __builtin_elementwise_fma(ex[1], hm2[1],
                    __builtin_elementwise_fma(ex[2], hm2[2],
                    ex[3] * hm2[3])));
        float sum = s2.x + s2.y;
        float ws  = w2s.x + w2s.y;
        float corrected = fmaxf(ha, fmaf(ws, fast_rcp(sum), 1e-6f));
        out[(size_t)(b0 + r) * V_ + c] = corrected;
    }
}

extern "C" void kernel_launch(void* const* d_in, const int* in_sizes, int n_in,
                              void* d_out, int out_size, void* d_ws, size_t ws_size,
                              hipStream_t stream) {
    const float* preds    = (const float*)d_in[0];
    const int*   mask_ids = (const int*)d_in[2];
    const float* W1       = (const float*)d_in[3];
    const float* b1       = (const float*)d_in[4];
    const float* W2       = (const float*)d_in[5];
    float* out = (float*)d_out;

    dim3 grid(NCOMPUTE + NCOPY);
    dim3 block(256);
    grad_attn_kernel<<<grid, block, 0, stream>>>(preds, mask_ids, W1, b1, W2, out);
}